// Round 1
// baseline (817.401 us; speedup 1.0000x reference)
//
#include <hip/hip_runtime.h>

// MPLayer: h = relu(concat(node_x, z) @ W_upd + b_upd)
//   z = where(deg>0, relu(segsum(concat(node_x[src], edge_x) @ W_pre + b_pre)), z_init)
// Rewrite: segsum commutes with the linear layer ->
//   scatter raw features, apply W_pre once per node (13.1 GFLOP -> 1.4 GFLOP).

#define N_NODES 100000
#define N_EDGES 1600000
#define ND 32
#define ED 32
#define OD 32
#define ZD 64   // ND+ED
#define UD 96   // 2*ND+ED

// K1: one wave (64 lanes) per edge. Lane l<32 -> node_x[src][l], lane>=32 ->
// edge_x[e][l-32]. 64 atomicAdds into S[dst*64 + l] (4 consecutive cachelines).
__global__ __launch_bounds__(256) void edge_scatter(
    const float* __restrict__ node_x, const float* __restrict__ edge_x,
    const int* __restrict__ src, const int* __restrict__ dst,
    float* __restrict__ S, float* __restrict__ deg)
{
    long tid = (long)blockIdx.x * 256 + threadIdx.x;
    int e = (int)(tid >> 6);
    int l = (int)(tid & 63);
    if (e >= N_EDGES) return;
    int s = src[e];
    int d = dst[e];
    float v = (l < ND) ? node_x[(long)s * ND + l]
                       : edge_x[(long)e * ED + (l - ND)];
    atomicAdd(&S[(long)d * ZD + l], v);
    if (l == 0) atomicAdd(&deg[d], 1.0f);
}

// K2: wave-per-node, lane-per-column (ZD=64). z = deg>0 ? relu(S@W_pre + deg*b_pre)
// : z_init. In-place overwrite of S is safe: each wave owns exactly one row and
// its store issues after all its loads (program order within the wave).
__global__ __launch_bounds__(256) void node_z(
    const float* __restrict__ z_init,
    const float* __restrict__ W_pre, const float* __restrict__ b_pre,
    float* __restrict__ S, const float* __restrict__ deg)
{
    __shared__ float Wl[ZD * ZD];   // 16 KB
    __shared__ float bl[ZD];
    for (int i = threadIdx.x; i < ZD * ZD; i += 256) Wl[i] = W_pre[i];
    if (threadIdx.x < ZD) bl[threadIdx.x] = b_pre[threadIdx.x];
    __syncthreads();

    int tid = blockIdx.x * 256 + threadIdx.x;
    int n = tid >> 6;      // wave-aligned: threads 0-63 -> node 0 of block, etc.
    int c = tid & 63;
    if (n >= N_NODES) return;

    float dg = deg[n];
    float out;
    if (dg > 0.0f) {
        float acc = dg * bl[c];
        const float* Srow = S + (long)n * ZD;
        #pragma unroll
        for (int k = 0; k < ZD; ++k) {
            // Srow[k]: wave-broadcast load (L1). Wl[k*64+c]: 64 lanes over 32
            // banks = 2 lanes/bank = conflict-free on gfx950.
            acc += Srow[k] * Wl[k * ZD + c];
        }
        out = fmaxf(acc, 0.0f);
    } else {
        out = z_init[(long)n * ZD + c];
    }
    S[(long)n * ZD + c] = out;   // S row now holds z
}

// K3: half-wave per node (OD=32 lanes). h = relu(concat(node_x, z) @ W_upd + b_upd).
__global__ __launch_bounds__(256) void node_h(
    const float* __restrict__ node_x,
    const float* __restrict__ W_upd, const float* __restrict__ b_upd,
    const float* __restrict__ Z, float* __restrict__ out)
{
    __shared__ float Wl[UD * OD];   // 12 KB
    __shared__ float bl[OD];
    for (int i = threadIdx.x; i < UD * OD; i += 256) Wl[i] = W_upd[i];
    if (threadIdx.x < OD) bl[threadIdx.x] = b_upd[threadIdx.x];
    __syncthreads();

    int tid = blockIdx.x * 256 + threadIdx.x;
    int n = tid >> 5;
    int c = tid & 31;
    if (n >= N_NODES) return;

    float acc = bl[c];
    const float* xr = node_x + (long)n * ND;
    const float* zr = Z + (long)n * ZD;
    #pragma unroll
    for (int k = 0; k < ND; ++k) acc += xr[k] * Wl[k * OD + c];
    #pragma unroll
    for (int k = 0; k < ZD; ++k) acc += zr[k] * Wl[(ND + k) * OD + c];
    out[(long)n * OD + c] = fmaxf(acc, 0.0f);
}

extern "C" void kernel_launch(void* const* d_in, const int* in_sizes, int n_in,
                              void* d_out, int out_size, void* d_ws, size_t ws_size,
                              hipStream_t stream)
{
    const float* node_x = (const float*)d_in[0];
    const float* edge_x = (const float*)d_in[1];
    const float* z_init = (const float*)d_in[2];
    const float* W_pre  = (const float*)d_in[3];
    const float* b_pre  = (const float*)d_in[4];
    const float* W_upd  = (const float*)d_in[5];
    const float* b_upd  = (const float*)d_in[6];
    const int*   src    = (const int*)d_in[7];
    const int*   dst    = (const int*)d_in[8];
    float* out = (float*)d_out;

    // Workspace layout: S [N*64] then deg [N]  (~26 MB)
    float* S   = (float*)d_ws;
    float* deg = S + (size_t)N_NODES * ZD;

    hipMemsetAsync(d_ws, 0, ((size_t)N_NODES * ZD + N_NODES) * sizeof(float), stream);

    {   // K1: E waves, 1 edge per wave
        long threads = (long)N_EDGES * 64;
        int blocks = (int)((threads + 255) / 256);
        edge_scatter<<<blocks, 256, 0, stream>>>(node_x, edge_x, src, dst, S, deg);
    }
    {   // K2
        int blocks = (N_NODES * ZD + 255) / 256;
        node_z<<<blocks, 256, 0, stream>>>(z_init, W_pre, b_pre, S, deg);
    }
    {   // K3
        int blocks = (N_NODES * OD + 255) / 256;
        node_h<<<blocks, 256, 0, stream>>>(node_x, W_upd, b_upd, S, out);
    }
}